// Round 8
// baseline (375.082 us; speedup 1.0000x reference)
//
#include <hip/hip_runtime.h>
#include <stdint.h>

// ---------------------------------------------------------------------------
// GCN: agg1 = A_hat x (pair-gather, no threefry)
//      h    = relu+drop(agg1 W1 + b1)   (MFMA GEMM, inline threefry dropout)
//      hw2  = h W2                      (MFMA GEMM, + layer-2 mask bitmap gen)
//      out  = relu+drop(A_hat hw2 + b2) (pair-gather + mask-bit test)
// CSR carries fused (src, weight) pairs; gather chain is pair->row->FMA.
// ---------------------------------------------------------------------------

#define N_NODES 50000
#define N_EDGES 800000
#define M_PAD   50048   // 391 * 128
#define IN_C 256
#define HID_C 512
#define OUT_C 256

typedef __attribute__((ext_vector_type(8))) short bf16x8;
typedef __attribute__((ext_vector_type(4))) float f32x4;

struct U2 { unsigned a, b; };

__host__ __device__ constexpr unsigned rotl32(unsigned x, int d) {
  return (x << d) | (x >> (32 - d));
}

#define TF_ROUND(r) { x0 += x1; x1 = rotl32(x1, (r)); x1 ^= x0; }

__host__ __device__ constexpr U2 threefry2x32(unsigned k0, unsigned k1,
                                              unsigned x0, unsigned x1) {
  unsigned ks2 = k0 ^ k1 ^ 0x1BD11BDAu;
  x0 += k0; x1 += k1;
  TF_ROUND(13) TF_ROUND(15) TF_ROUND(26) TF_ROUND(6)  x0 += k1;  x1 += ks2 + 1u;
  TF_ROUND(17) TF_ROUND(29) TF_ROUND(16) TF_ROUND(24) x0 += ks2; x1 += k0 + 2u;
  TF_ROUND(13) TF_ROUND(15) TF_ROUND(26) TF_ROUND(6)  x0 += k0;  x1 += k1 + 3u;
  TF_ROUND(17) TF_ROUND(29) TF_ROUND(16) TF_ROUND(24) x0 += k1;  x1 += ks2 + 4u;
  TF_ROUND(13) TF_ROUND(15) TF_ROUND(26) TF_ROUND(6)  x0 += ks2; x1 += k0 + 5u;
  return U2{x0, x1};
}

__device__ __forceinline__ float drop_apply(float v, unsigned idx, unsigned k0, unsigned k1) {
  v = fmaxf(v, 0.f);
  U2 r = threefry2x32(k0, k1, 0u, idx);
  unsigned bits = r.a ^ r.b;
  return (bits >> 31) ? 0.f : v * 2.0f;
}

__device__ __forceinline__ ushort f2b(float f) {  // RTNE
  unsigned u = __builtin_bit_cast(unsigned, f);
  unsigned r = (u + 0x7fffu + ((u >> 16) & 1u)) >> 16;
  return (ushort)r;
}
__device__ __forceinline__ float b2f_hi(unsigned u) {
  return __builtin_bit_cast(float, u & 0xffff0000u);
}
__device__ __forceinline__ float b2f_lo(unsigned u) {
  return __builtin_bit_cast(float, u << 16);
}

__device__ __forceinline__ void acc8(float (&a)[8], uint4 u, float wgt) {
  a[0] += b2f_lo(u.x) * wgt; a[1] += b2f_hi(u.x) * wgt;
  a[2] += b2f_lo(u.y) * wgt; a[3] += b2f_hi(u.y) * wgt;
  a[4] += b2f_lo(u.z) * wgt; a[5] += b2f_hi(u.z) * wgt;
  a[6] += b2f_lo(u.w) * wgt; a[7] += b2f_hi(u.w) * wgt;
}

__device__ __forceinline__ void gload16(const void* g, void* l) {
  __builtin_amdgcn_global_load_lds(
      (const __attribute__((address_space(1))) void*)g,
      (__attribute__((address_space(3))) void*)l, 16, 0, 0);
}

// ---------------------------------------------------------------------------
// degree / dinv / scan / CSR build (CSR entry = {src, dinv[src]})
// ---------------------------------------------------------------------------
__global__ void deg_kernel(const int* __restrict__ col, int* __restrict__ cnt, int E) {
  int e = blockIdx.x * 256 + threadIdx.x;
  if (e < E) atomicAdd(&cnt[col[e]], 1);
}

__global__ void dinv_kernel(const int* __restrict__ cnt, float* __restrict__ dinv, int N) {
  int n = blockIdx.x * 256 + threadIdx.x;
  if (n < N) dinv[n] = rsqrtf((float)cnt[n] + 1.0f);
}

__global__ __launch_bounds__(1024) void scan_local(const int* __restrict__ cnt,
                                                   int* __restrict__ indptr,
                                                   int* __restrict__ chunkSums, int n) {
  __shared__ int s[1024];
  int gid = blockIdx.x * 1024 + threadIdx.x;
  int v = (gid < n) ? cnt[gid] : 0;
  s[threadIdx.x] = v;
  __syncthreads();
#pragma unroll
  for (int off = 1; off < 1024; off <<= 1) {
    int t = (threadIdx.x >= off) ? s[threadIdx.x - off] : 0;
    __syncthreads();
    s[threadIdx.x] += t;
    __syncthreads();
  }
  if (gid < n) indptr[gid] = s[threadIdx.x] - v;
  if (threadIdx.x == 1023) chunkSums[blockIdx.x] = s[1023];
}

__global__ void scan_chunks(int* __restrict__ chunkSums, int nChunks) {
  if (threadIdx.x == 0 && blockIdx.x == 0) {
    int acc = 0;
    for (int i = 0; i < nChunks; ++i) { int t = chunkSums[i]; chunkSums[i] = acc; acc += t; }
  }
}

__global__ void add_offsets(int* __restrict__ indptr, const int* __restrict__ chunkSums,
                            int n, int total) {
  int gid = blockIdx.x * 256 + threadIdx.x;
  if (gid < n) indptr[gid] += chunkSums[gid >> 10];
  if (gid == 0) indptr[n] = total;
}

__global__ void build_csr(const int* __restrict__ row, const int* __restrict__ col,
                          const int* __restrict__ indptr, int* __restrict__ cursor,
                          const float* __restrict__ dinv,
                          int2* __restrict__ srcW, int E) {
  int e = blockIdx.x * 256 + threadIdx.x;
  if (e < E) {
    int r = row[e];
    int c = col[e];
    int p = indptr[c] + atomicAdd(&cursor[c], 1);
    srcW[p] = make_int2(r, __builtin_bit_cast(int, dinv[r]));
  }
}

// ---------------------------------------------------------------------------
// converts
// ---------------------------------------------------------------------------
__global__ void cvt_f32_bf16(const float* __restrict__ in, ushort* __restrict__ out, int n4) {
  int i = blockIdx.x * 256 + threadIdx.x;
  if (i < n4) {
    float4 v = *(const float4*)(in + (size_t)i * 4);
    ushort4 o = make_ushort4(f2b(v.x), f2b(v.y), f2b(v.z), f2b(v.w));
    *(ushort4*)(out + (size_t)i * 4) = o;
  }
}

template <int LOGK>
__global__ void wT_kernel(const float* __restrict__ W, ushort* __restrict__ WT, int N, int total) {
  int i = blockIdx.x * 256 + threadIdx.x;
  if (i < total) {
    int k = i & ((1 << LOGK) - 1);
    int n = i >> LOGK;
    WT[i] = f2b(W[(size_t)k * N + n]);
  }
}

// ---------------------------------------------------------------------------
// pair-gather over CSR: one wave per node, 2 edges in parallel (sub = lane>>5),
// 32 lanes x 16B (8 features) per edge. 8-edge unrolled main loop.
// EPI=false: bf16 out. EPI=true: bias+relu+mask2-bit dropout, fp32 out.
// ---------------------------------------------------------------------------
template <bool EPI>
__global__ __launch_bounds__(256) void gather_pair(const ushort* __restrict__ X,
                                                   const int* __restrict__ indptr,
                                                   const int2* __restrict__ srcW,
                                                   const float* __restrict__ dinv,
                                                   const float* __restrict__ bias,
                                                   void* __restrict__ outp,
                                                   const unsigned char* __restrict__ mask2,
                                                   int N) {
  int wid = (blockIdx.x * 256 + threadIdx.x) >> 6;
  int lane = threadIdx.x & 63;
  if (wid >= N) return;
  const int sub = lane >> 5;
  const int fi = lane & 31;
  const int f0 = fi * 8;
  int beg = __builtin_amdgcn_readfirstlane(indptr[wid]);
  int end = __builtin_amdgcn_readfirstlane(indptr[wid + 1]);
  float dc = dinv[wid];

  float a[8] = {};
  if (sub == 0) {  // self-loop term
    uint4 u = *(const uint4*)(X + (size_t)wid * 256 + f0);
    acc8(a, u, dc);
  }
  int eb = beg;
  for (; eb + 8 <= end; eb += 8) {
    int2 q0 = srcW[eb + 0 + sub];
    int2 q1 = srcW[eb + 2 + sub];
    int2 q2 = srcW[eb + 4 + sub];
    int2 q3 = srcW[eb + 6 + sub];
    uint4 u0 = *(const uint4*)(X + (size_t)q0.x * 256 + f0);
    uint4 u1 = *(const uint4*)(X + (size_t)q1.x * 256 + f0);
    uint4 u2 = *(const uint4*)(X + (size_t)q2.x * 256 + f0);
    uint4 u3 = *(const uint4*)(X + (size_t)q3.x * 256 + f0);
    acc8(a, u0, __builtin_bit_cast(float, q0.y));
    acc8(a, u1, __builtin_bit_cast(float, q1.y));
    acc8(a, u2, __builtin_bit_cast(float, q2.y));
    acc8(a, u3, __builtin_bit_cast(float, q3.y));
  }
  for (int e = eb + sub; e < end; e += 2) {
    int2 q = srcW[e];
    uint4 u = *(const uint4*)(X + (size_t)q.x * 256 + f0);
    acc8(a, u, __builtin_bit_cast(float, q.y));
  }
  // merge the two edge-halves
#pragma unroll
  for (int j = 0; j < 8; ++j) {
    a[j] += __shfl_xor(a[j], 32);
    a[j] *= dc;
  }

  if (EPI) {
    float4 bv0 = *(const float4*)(bias + f0);
    float4 bv1 = *(const float4*)(bias + f0 + 4);
    unsigned mk = mask2[(size_t)wid * 32 + fi];
    float v[8];
    v[0] = fmaxf(a[0] + bv0.x, 0.f); v[1] = fmaxf(a[1] + bv0.y, 0.f);
    v[2] = fmaxf(a[2] + bv0.z, 0.f); v[3] = fmaxf(a[3] + bv0.w, 0.f);
    v[4] = fmaxf(a[4] + bv1.x, 0.f); v[5] = fmaxf(a[5] + bv1.y, 0.f);
    v[6] = fmaxf(a[6] + bv1.z, 0.f); v[7] = fmaxf(a[7] + bv1.w, 0.f);
#pragma unroll
    for (int j = 0; j < 8; ++j) v[j] = ((mk >> j) & 1u) ? 0.f : v[j] * 2.0f;
    float4 o;
    if (sub == 0) o = make_float4(v[0], v[1], v[2], v[3]);
    else          o = make_float4(v[4], v[5], v[6], v[7]);
    *(float4*)((float*)outp + (size_t)wid * 256 + f0 + sub * 4) = o;
  } else {
    uint2 o;
    if (sub == 0) {
      o.x = (unsigned)f2b(a[0]) | ((unsigned)f2b(a[1]) << 16);
      o.y = (unsigned)f2b(a[2]) | ((unsigned)f2b(a[3]) << 16);
    } else {
      o.x = (unsigned)f2b(a[4]) | ((unsigned)f2b(a[5]) << 16);
      o.y = (unsigned)f2b(a[6]) | ((unsigned)f2b(a[7]) << 16);
    }
    *(uint2*)((ushort*)outp + (size_t)wid * 256 + f0 + sub * 4) = o;
  }
}

// ---------------------------------------------------------------------------
// bf16 MFMA GEMM: C[M,N] = A[M,K] @ BT[N,K]^T.  128x128 tile, BK=64, 4 waves,
// double-buffered LDS + prefetch, XOR-swizzled stage/read, coalesced C-store.
// MODE 1: inline threefry dropout (bias+relu+drop), bf16 out.
// MODE 2: plain bf16 out + layer-2 dropout bitmask generation.
// ---------------------------------------------------------------------------
template <int MODE>
__global__ __launch_bounds__(256) void gemm_bf16(const ushort* __restrict__ A,
                                                 const ushort* __restrict__ BT,
                                                 ushort* __restrict__ C,
                                                 int M, int K, int N,
                                                 const float* __restrict__ bias,
                                                 unsigned char* __restrict__ maskOut,
                                                 unsigned kk0, unsigned kk1) {
  __shared__ __align__(16) ushort lds[4 * 128 * 64];  // A0 A1 B0 B1 (16KB each)
  const int tid = threadIdx.x;
  const int lane = tid & 63;
  const int wv = tid >> 6;
  const int wr = wv >> 1, wc = wv & 1;
  const int bm = blockIdx.x * 128;
  const int bn = blockIdx.y * 128;

  f32x4 acc[4][4] = {};
  const int xorv = (lane & 7) << 4;

  auto stage = [&](int buf, int k0) {
#pragma unroll
    for (int l = 0; l < 4; ++l) {
      int cid = l * 256 + tid;
      int row = cid >> 3;
      int kcol = ((cid & 7) ^ (row & 7)) * 8;
      gload16(A + (size_t)(bm + row) * K + k0 + kcol, (void*)(lds + buf * 8192 + cid * 8));
      gload16(BT + (size_t)(bn + row) * K + k0 + kcol, (void*)(lds + (2 + buf) * 8192 + cid * 8));
    }
  };

  const int nt = K >> 6;
  stage(0, 0);
  __syncthreads();
  int cur = 0;
  for (int t = 0; t < nt; ++t) {
    if (t + 1 < nt) stage(cur ^ 1, (t + 1) << 6);
    const char* Ab = (const char*)(lds + cur * 8192);
    const char* Bb = (const char*)(lds + (2 + cur) * 8192);
#pragma unroll
    for (int ks = 0; ks < 2; ++ks) {
      bf16x8 af[4], bf[4];
      const int kb = (ks * 64 + (lane >> 4) * 16) ^ xorv;
#pragma unroll
      for (int i = 0; i < 4; ++i) {
        int arow = wr * 64 + i * 16 + (lane & 15);
        af[i] = *(const bf16x8*)(Ab + arow * 128 + kb);
        int brow = wc * 64 + i * 16 + (lane & 15);
        bf[i] = *(const bf16x8*)(Bb + brow * 128 + kb);
      }
#pragma unroll
      for (int m = 0; m < 4; ++m)
#pragma unroll
        for (int n = 0; n < 4; ++n)
          acc[m][n] = __builtin_amdgcn_mfma_f32_16x16x32_bf16(af[m], bf[n], acc[m][n], 0, 0, 0);
    }
    __syncthreads();
    cur ^= 1;
  }

  // ---- epilogue: acc -> (bias/relu/drop) -> bf16 -> LDS [128][132] -> store
  ushort* Csm = (ushort*)lds;
  const int rowoff = wr * 64 + ((lane >> 4) << 2);
  const int coloff = wc * 64 + (lane & 15);
  float bias_v[4];
  if (MODE == 1) {
#pragma unroll
    for (int n = 0; n < 4; ++n) bias_v[n] = bias[bn + coloff + n * 16];
  }
#pragma unroll
  for (int m = 0; m < 4; ++m) {
#pragma unroll
    for (int r = 0; r < 4; ++r) {
      int lrow = rowoff + m * 16 + r;
#pragma unroll
      for (int n = 0; n < 4; ++n) {
        float v = acc[m][n][r];
        if (MODE == 1) {
          unsigned idx = (unsigned)(bm + lrow) * (unsigned)N + (unsigned)(bn + coloff + n * 16);
          v = drop_apply(v + bias_v[n], idx, kk0, kk1);
        }
        Csm[lrow * 132 + coloff + n * 16] = f2b(v);
      }
    }
  }
  __syncthreads();
  {
    int row = tid >> 1, ch = (tid & 1) * 64;
    const ushort* src = Csm + row * 132 + ch;
    ushort* dst = C + (size_t)(bm + row) * N + bn + ch;
#pragma unroll
    for (int j = 0; j < 8; ++j)
      *(bf16x8*)(dst + j * 8) = *(const bf16x8*)(src + j * 8);
    if (MODE == 2) {
      // layer-2 dropout bitmask for out[grow][bn+ch .. +64)
      int grow = bm + row;
      unsigned base = (unsigned)grow * (unsigned)N + (unsigned)(bn + ch);
      unsigned long long mword = 0;
#pragma unroll
      for (int j = 0; j < 64; ++j) {
        U2 rr = threefry2x32(kk0, kk1, 0u, base + (unsigned)j);
        mword |= (unsigned long long)(((rr.a ^ rr.b) >> 31) & 1u) << j;
      }
      *(unsigned long long*)(maskOut + (size_t)(base >> 3)) = mword;
    }
  }
}

// ---------------------------------------------------------------------------
extern "C" void kernel_launch(void* const* d_in, const int* in_sizes, int n_in,
                              void* d_out, int out_size, void* d_ws, size_t ws_size,
                              hipStream_t stream) {
  const float* x  = (const float*)d_in[0];
  const int*   ei = (const int*)d_in[1];
  const float* W1 = (const float*)d_in[2];
  const float* b1 = (const float*)d_in[3];
  const float* W2 = (const float*)d_in[4];
  const float* b2 = (const float*)d_in[5];
  float* out = (float*)d_out;
  (void)in_sizes; (void)n_in; (void)out_size; (void)ws_size;

  const int* row = ei;
  const int* col = ei + N_EDGES;

  // workspace layout (bytes)
  char* ws = (char*)d_ws;
  float*  dinv      = (float*) (ws);                           // 200 KB
  int*    cnt       = (int*)   (ws + (1u << 18));              // 200 KB
  int*    indptr    = (int*)   (ws + (2u << 18));              // 200 KB + 4
  int*    cursor    = (int*)   (ws + (3u << 18));              // 200 KB
  int*    chunkSums = (int*)   (ws + (1u << 20));              // tiny
  int2*   srcW      = (int2*)  (ws + 2u * (1u << 20));         // 6.4 MB
  ushort* W1T       = (ushort*)(ws + 9u * (1u << 20));         // 256 KB [512][256]
  ushort* W2T       = (ushort*)(ws + 9u * (1u << 20) + (1u << 19)); // 256 KB
  unsigned char* mask2 = (unsigned char*)(ws + 10u * (1u << 20)); // 1.6 MB
  ushort* x16       = (ushort*)(ws + 14u * (1u << 20));        // 25.6 MB [50000][256]
  ushort* aggB      = (ushort*)(ws + 40u * (1u << 20));        // 25.6 MB [M_PAD][256]
  ushort* h         = (ushort*)(ws + 66u * (1u << 20));        // 51.2 MB [M_PAD][512]
  ushort* hw2       = (ushort*)(ws + 118u* (1u << 20));        // 25.6 MB [M_PAD][256]

  constexpr U2 K1 = threefry2x32(0u, 42u, 0u, 0u);
  constexpr U2 K2 = threefry2x32(0u, 42u, 0u, 1u);

  // ---- CSR build ----
  (void)hipMemsetAsync(cnt, 0, N_NODES * sizeof(int), stream);
  (void)hipMemsetAsync(cursor, 0, N_NODES * sizeof(int), stream);
  deg_kernel<<<(N_EDGES + 255) / 256, 256, 0, stream>>>(col, cnt, N_EDGES);
  dinv_kernel<<<(N_NODES + 255) / 256, 256, 0, stream>>>(cnt, dinv, N_NODES);
  const int nChunks = (N_NODES + 1023) / 1024;
  scan_local<<<nChunks, 1024, 0, stream>>>(cnt, indptr, chunkSums, N_NODES);
  scan_chunks<<<1, 64, 0, stream>>>(chunkSums, nChunks);
  add_offsets<<<(N_NODES + 255) / 256, 256, 0, stream>>>(indptr, chunkSums, N_NODES, N_EDGES);
  build_csr<<<(N_EDGES + 255) / 256, 256, 0, stream>>>(row, col, indptr, cursor, dinv, srcW, N_EDGES);

  // ---- converts ----
  cvt_f32_bf16<<<(N_NODES * IN_C / 4 + 255) / 256, 256, 0, stream>>>(x, x16, N_NODES * IN_C / 4);
  wT_kernel<8><<<(IN_C * HID_C + 255) / 256, 256, 0, stream>>>(W1, W1T, HID_C, IN_C * HID_C);
  wT_kernel<9><<<(HID_C * OUT_C + 255) / 256, 256, 0, stream>>>(W2, W2T, OUT_C, HID_C * OUT_C);
  (void)hipMemsetAsync(aggB + (size_t)N_NODES * IN_C, 0, (size_t)(M_PAD - N_NODES) * IN_C * 2, stream);

  // ---- layer 1 ----
  gather_pair<false><<<(N_NODES + 3) / 4, 256, 0, stream>>>(
      x16, indptr, srcW, dinv, nullptr, aggB, nullptr, N_NODES);
  gemm_bf16<1><<<dim3(M_PAD / 128, HID_C / 128), 256, 0, stream>>>(
      aggB, W1T, h, M_PAD, IN_C, HID_C, b1, nullptr, K1.a, K1.b);

  // ---- layer 2 ----
  gemm_bf16<2><<<dim3(M_PAD / 128, OUT_C / 128), 256, 0, stream>>>(
      h, W2T, hw2, M_PAD, HID_C, OUT_C, nullptr, mask2, K2.a, K2.b);
  gather_pair<true><<<(N_NODES + 3) / 4, 256, 0, stream>>>(
      hw2, indptr, srcW, dinv, b2, out, mask2, N_NODES);
}

// Round 9
// 370.121 us; speedup vs baseline: 1.0134x; 1.0134x over previous
//
#include <hip/hip_runtime.h>
#include <stdint.h>

// ---------------------------------------------------------------------------
// GCN: agg1 = A_hat x (16-deep gather, no threefry)
//      h    = relu+drop(agg1 W1 + b1)   (MFMA GEMM, inline threefry dropout)
//      hw2  = h W2                      (MFMA GEMM, + layer-2 mask bitmap gen)
//      out  = relu+drop(A_hat hw2 + b2) (16-deep gather + mask-bit test)
// CSR carries fused (src, weight) pairs; gather chain is pair->row->FMA.
// GEMM: single-buffer 32KB staging (m97 2-barrier structure) -> 4 blocks/CU.
// ---------------------------------------------------------------------------

#define N_NODES 50000
#define N_EDGES 800000
#define M_PAD   50048   // 391 * 128
#define IN_C 256
#define HID_C 512
#define OUT_C 256

typedef __attribute__((ext_vector_type(8))) short bf16x8;
typedef __attribute__((ext_vector_type(4))) float f32x4;

struct U2 { unsigned a, b; };

__host__ __device__ constexpr unsigned rotl32(unsigned x, int d) {
  return (x << d) | (x >> (32 - d));
}

#define TF_ROUND(r) { x0 += x1; x1 = rotl32(x1, (r)); x1 ^= x0; }

__host__ __device__ constexpr U2 threefry2x32(unsigned k0, unsigned k1,
                                              unsigned x0, unsigned x1) {
  unsigned ks2 = k0 ^ k1 ^ 0x1BD11BDAu;
  x0 += k0; x1 += k1;
  TF_ROUND(13) TF_ROUND(15) TF_ROUND(26) TF_ROUND(6)  x0 += k1;  x1 += ks2 + 1u;
  TF_ROUND(17) TF_ROUND(29) TF_ROUND(16) TF_ROUND(24) x0 += ks2; x1 += k0 + 2u;
  TF_ROUND(13) TF_ROUND(15) TF_ROUND(26) TF_ROUND(6)  x0 += k0;  x1 += k1 + 3u;
  TF_ROUND(17) TF_ROUND(29) TF_ROUND(16) TF_ROUND(24) x0 += k1;  x1 += ks2 + 4u;
  TF_ROUND(13) TF_ROUND(15) TF_ROUND(26) TF_ROUND(6)  x0 += ks2; x1 += k0 + 5u;
  return U2{x0, x1};
}

__device__ __forceinline__ float drop_apply(float v, unsigned idx, unsigned k0, unsigned k1) {
  v = fmaxf(v, 0.f);
  U2 r = threefry2x32(k0, k1, 0u, idx);
  unsigned bits = r.a ^ r.b;
  return (bits >> 31) ? 0.f : v * 2.0f;
}

__device__ __forceinline__ ushort f2b(float f) {  // RTNE
  unsigned u = __builtin_bit_cast(unsigned, f);
  unsigned r = (u + 0x7fffu + ((u >> 16) & 1u)) >> 16;
  return (ushort)r;
}
__device__ __forceinline__ float b2f_hi(unsigned u) {
  return __builtin_bit_cast(float, u & 0xffff0000u);
}
__device__ __forceinline__ float b2f_lo(unsigned u) {
  return __builtin_bit_cast(float, u << 16);
}

__device__ __forceinline__ void acc4(float (&a)[4], uint2 u, float wgt) {
  a[0] += b2f_lo(u.x) * wgt; a[1] += b2f_hi(u.x) * wgt;
  a[2] += b2f_lo(u.y) * wgt; a[3] += b2f_hi(u.y) * wgt;
}

__device__ __forceinline__ void gload16(const void* g, void* l) {
  __builtin_amdgcn_global_load_lds(
      (const __attribute__((address_space(1))) void*)g,
      (__attribute__((address_space(3))) void*)l, 16, 0, 0);
}

// ---------------------------------------------------------------------------
// degree / dinv / scan / CSR build (CSR entry = {src, dinv[src]})
// ---------------------------------------------------------------------------
__global__ void deg_kernel(const int* __restrict__ col, int* __restrict__ cnt, int E) {
  int e = blockIdx.x * 256 + threadIdx.x;
  if (e < E) atomicAdd(&cnt[col[e]], 1);
}

__global__ void dinv_kernel(const int* __restrict__ cnt, float* __restrict__ dinv, int N) {
  int n = blockIdx.x * 256 + threadIdx.x;
  if (n < N) dinv[n] = rsqrtf((float)cnt[n] + 1.0f);
}

__global__ __launch_bounds__(1024) void scan_local(const int* __restrict__ cnt,
                                                   int* __restrict__ indptr,
                                                   int* __restrict__ chunkSums, int n) {
  __shared__ int s[1024];
  int gid = blockIdx.x * 1024 + threadIdx.x;
  int v = (gid < n) ? cnt[gid] : 0;
  s[threadIdx.x] = v;
  __syncthreads();
#pragma unroll
  for (int off = 1; off < 1024; off <<= 1) {
    int t = (threadIdx.x >= off) ? s[threadIdx.x - off] : 0;
    __syncthreads();
    s[threadIdx.x] += t;
    __syncthreads();
  }
  if (gid < n) indptr[gid] = s[threadIdx.x] - v;
  if (threadIdx.x == 1023) chunkSums[blockIdx.x] = s[1023];
}

__global__ void scan_chunks(int* __restrict__ chunkSums, int nChunks) {
  if (threadIdx.x == 0 && blockIdx.x == 0) {
    int acc = 0;
    for (int i = 0; i < nChunks; ++i) { int t = chunkSums[i]; chunkSums[i] = acc; acc += t; }
  }
}

__global__ void add_offsets(int* __restrict__ indptr, const int* __restrict__ chunkSums,
                            int n, int total) {
  int gid = blockIdx.x * 256 + threadIdx.x;
  if (gid < n) indptr[gid] += chunkSums[gid >> 10];
  if (gid == 0) indptr[n] = total;
}

__global__ void build_csr(const int* __restrict__ row, const int* __restrict__ col,
                          const int* __restrict__ indptr, int* __restrict__ cursor,
                          const float* __restrict__ dinv,
                          int2* __restrict__ srcW, int E) {
  int e = blockIdx.x * 256 + threadIdx.x;
  if (e < E) {
    int r = row[e];
    int c = col[e];
    int p = indptr[c] + atomicAdd(&cursor[c], 1);
    srcW[p] = make_int2(r, __builtin_bit_cast(int, dinv[r]));
  }
}

// ---------------------------------------------------------------------------
// converts
// ---------------------------------------------------------------------------
__global__ void cvt_f32_bf16(const float* __restrict__ in, ushort* __restrict__ out, int n4) {
  int i = blockIdx.x * 256 + threadIdx.x;
  if (i < n4) {
    float4 v = *(const float4*)(in + (size_t)i * 4);
    ushort4 o = make_ushort4(f2b(v.x), f2b(v.y), f2b(v.z), f2b(v.w));
    *(ushort4*)(out + (size_t)i * 4) = o;
  }
}

template <int LOGK>
__global__ void wT_kernel(const float* __restrict__ W, ushort* __restrict__ WT, int N, int total) {
  int i = blockIdx.x * 256 + threadIdx.x;
  if (i < total) {
    int k = i & ((1 << LOGK) - 1);
    int n = i >> LOGK;
    WT[i] = f2b(W[(size_t)k * N + n]);
  }
}

// ---------------------------------------------------------------------------
// gather over CSR pairs: one wave per node, 64 lanes x 8B = full 512B row,
// explicit 16-deep load batches (arrays, static indices) for MLP.
// EPI=false: bf16 out. EPI=true: bias+relu+mask2-bit dropout, fp32 out.
// ---------------------------------------------------------------------------
template <bool EPI>
__global__ __launch_bounds__(256, 4) void gather16(const ushort* __restrict__ X,
                                                   const int* __restrict__ indptr,
                                                   const int2* __restrict__ srcW,
                                                   const float* __restrict__ dinv,
                                                   const float* __restrict__ bias,
                                                   void* __restrict__ outp,
                                                   const unsigned char* __restrict__ mask2,
                                                   int N) {
  int wid = (blockIdx.x * 256 + threadIdx.x) >> 6;
  int lane = threadIdx.x & 63;
  if (wid >= N) return;
  const int f0 = lane * 4;
  int beg = __builtin_amdgcn_readfirstlane(indptr[wid]);
  int end = __builtin_amdgcn_readfirstlane(indptr[wid + 1]);
  float dc = dinv[wid];

  float a[4] = {};
  {  // self-loop term
    uint2 u = *(const uint2*)(X + (size_t)wid * 256 + f0);
    acc4(a, u, dc);
  }
  int e = beg;
  for (; e + 16 <= end; e += 16) {
    int2 q[16];
#pragma unroll
    for (int j = 0; j < 16; ++j) q[j] = srcW[e + j];
    uint2 u[16];
#pragma unroll
    for (int j = 0; j < 16; ++j)
      u[j] = *(const uint2*)(X + (size_t)q[j].x * 256 + f0);
#pragma unroll
    for (int j = 0; j < 16; ++j)
      acc4(a, u[j], __builtin_bit_cast(float, q[j].y));
  }
  for (; e + 4 <= end; e += 4) {
    int2 q[4];
#pragma unroll
    for (int j = 0; j < 4; ++j) q[j] = srcW[e + j];
    uint2 u[4];
#pragma unroll
    for (int j = 0; j < 4; ++j)
      u[j] = *(const uint2*)(X + (size_t)q[j].x * 256 + f0);
#pragma unroll
    for (int j = 0; j < 4; ++j)
      acc4(a, u[j], __builtin_bit_cast(float, q[j].y));
  }
  for (; e < end; ++e) {
    int2 q = srcW[e];
    uint2 u = *(const uint2*)(X + (size_t)q.x * 256 + f0);
    acc4(a, u, __builtin_bit_cast(float, q.y));
  }
#pragma unroll
  for (int j = 0; j < 4; ++j) a[j] *= dc;

  if (EPI) {
    float4 bv = *(const float4*)(bias + f0);
    unsigned mk = mask2[(size_t)wid * 32 + (lane >> 1)];
    int sh = (lane & 1) * 4;
    float v0 = fmaxf(a[0] + bv.x, 0.f);
    float v1 = fmaxf(a[1] + bv.y, 0.f);
    float v2 = fmaxf(a[2] + bv.z, 0.f);
    float v3 = fmaxf(a[3] + bv.w, 0.f);
    v0 = ((mk >> (sh + 0)) & 1u) ? 0.f : v0 * 2.0f;
    v1 = ((mk >> (sh + 1)) & 1u) ? 0.f : v1 * 2.0f;
    v2 = ((mk >> (sh + 2)) & 1u) ? 0.f : v2 * 2.0f;
    v3 = ((mk >> (sh + 3)) & 1u) ? 0.f : v3 * 2.0f;
    *(float4*)((float*)outp + (size_t)wid * 256 + f0) = make_float4(v0, v1, v2, v3);
  } else {
    uint2 o;
    o.x = (unsigned)f2b(a[0]) | ((unsigned)f2b(a[1]) << 16);
    o.y = (unsigned)f2b(a[2]) | ((unsigned)f2b(a[3]) << 16);
    *(uint2*)((ushort*)outp + (size_t)wid * 256 + f0) = o;
  }
}

// ---------------------------------------------------------------------------
// bf16 MFMA GEMM: C[M,N] = A[M,K] @ BT[N,K]^T.  128x128 tile, BK=64, 4 waves,
// SINGLE-buffer 32KB staging (2-barrier m97 structure) -> 4 blocks/CU.
// XOR-swizzled stage/read, coalesced bf16 C-store via LDS transpose.
// MODE 1: inline threefry dropout (bias+relu+drop), bf16 out.
// MODE 2: plain bf16 out + layer-2 dropout bitmask generation.
// ---------------------------------------------------------------------------
template <int MODE>
__global__ __launch_bounds__(256) void gemm_bf16(const ushort* __restrict__ A,
                                                 const ushort* __restrict__ BT,
                                                 ushort* __restrict__ C,
                                                 int M, int K, int N,
                                                 const float* __restrict__ bias,
                                                 unsigned char* __restrict__ maskOut,
                                                 unsigned kk0, unsigned kk1) {
  // staging: A 8192 + B 8192 ushorts (32KB). epilogue Csm [128][132] = 16896.
  __shared__ __align__(16) ushort lds[16896];
  const int tid = threadIdx.x;
  const int lane = tid & 63;
  const int wv = tid >> 6;
  const int wr = wv >> 1, wc = wv & 1;
  const int bm = blockIdx.x * 128;
  const int bn = blockIdx.y * 128;

  f32x4 acc[4][4] = {};
  const int xorv = (lane & 7) << 4;

  const int nt = K >> 6;
  for (int t = 0; t < nt; ++t) {
    const int k0 = t << 6;
#pragma unroll
    for (int l = 0; l < 4; ++l) {
      int cid = l * 256 + tid;
      int row = cid >> 3;
      int kcol = ((cid & 7) ^ (row & 7)) * 8;
      gload16(A + (size_t)(bm + row) * K + k0 + kcol, (void*)(lds + cid * 8));
      gload16(BT + (size_t)(bn + row) * K + k0 + kcol, (void*)(lds + 8192 + cid * 8));
    }
    __syncthreads();
    const char* Ab = (const char*)lds;
    const char* Bb = (const char*)(lds + 8192);
#pragma unroll
    for (int ks = 0; ks < 2; ++ks) {
      bf16x8 af[4], bf[4];
      const int kb = (ks * 64 + (lane >> 4) * 16) ^ xorv;
#pragma unroll
      for (int i = 0; i < 4; ++i) {
        int arow = wr * 64 + i * 16 + (lane & 15);
        af[i] = *(const bf16x8*)(Ab + arow * 128 + kb);
        int brow = wc * 64 + i * 16 + (lane & 15);
        bf[i] = *(const bf16x8*)(Bb + brow * 128 + kb);
      }
#pragma unroll
      for (int m = 0; m < 4; ++m)
#pragma unroll
        for (int n = 0; n < 4; ++n)
          acc[m][n] = __builtin_amdgcn_mfma_f32_16x16x32_bf16(af[m], bf[n], acc[m][n], 0, 0, 0);
    }
    __syncthreads();
  }

  // ---- epilogue: acc -> (bias/relu/drop) -> bf16 -> LDS [128][132] -> store
  ushort* Csm = (ushort*)lds;
  const int rowoff = wr * 64 + ((lane >> 4) << 2);
  const int coloff = wc * 64 + (lane & 15);
  float bias_v[4];
  if (MODE == 1) {
#pragma unroll
    for (int n = 0; n < 4; ++n) bias_v[n] = bias[bn + coloff + n * 16];
  }
#pragma unroll
  for (int m = 0; m < 4; ++m) {
#pragma unroll
    for (int r = 0; r < 4; ++r) {
      int lrow = rowoff + m * 16 + r;
#pragma unroll
      for (int n = 0; n < 4; ++n) {
        float v = acc[m][n][r];
        if (MODE == 1) {
          unsigned idx = (unsigned)(bm + lrow) * (unsigned)N + (unsigned)(bn + coloff + n * 16);
          v = drop_apply(v + bias_v[n], idx, kk0, kk1);
        }
        Csm[lrow * 132 + coloff + n * 16] = f2b(v);
      }
    }
  }
  __syncthreads();
  {
    int row = tid >> 1, ch = (tid & 1) * 64;
    const ushort* src = Csm + row * 132 + ch;
    ushort* dst = C + (size_t)(bm + row) * N + bn + ch;
#pragma unroll
    for (int j = 0; j < 8; ++j)
      *(bf16x8*)(dst + j * 8) = *(const bf16x8*)(src + j * 8);
    if (MODE == 2) {
      // layer-2 dropout bitmask for out[grow][bn+ch .. +64)
      int grow = bm + row;
      unsigned base = (unsigned)grow * (unsigned)N + (unsigned)(bn + ch);
      unsigned long long mword = 0;
#pragma unroll
      for (int j = 0; j < 64; ++j) {
        U2 rr = threefry2x32(kk0, kk1, 0u, base + (unsigned)j);
        mword |= (unsigned long long)(((rr.a ^ rr.b) >> 31) & 1u) << j;
      }
      *(unsigned long long*)(maskOut + (size_t)(base >> 3)) = mword;
    }
  }
}

// ---------------------------------------------------------------------------
extern "C" void kernel_launch(void* const* d_in, const int* in_sizes, int n_in,
                              void* d_out, int out_size, void* d_ws, size_t ws_size,
                              hipStream_t stream) {
  const float* x  = (const float*)d_in[0];
  const int*   ei = (const int*)d_in[1];
  const float* W1 = (const float*)d_in[2];
  const float* b1 = (const float*)d_in[3];
  const float* W2 = (const float*)d_in[4];
  const float* b2 = (const float*)d_in[5];
  float* out = (float*)d_out;
  (void)in_sizes; (void)n_in; (void)out_size; (void)ws_size;

  const int* row = ei;
  const int* col = ei + N_EDGES;

  // workspace layout (bytes)
  char* ws = (char*)d_ws;
  float*  dinv      = (float*) (ws);                           // 200 KB
  int*    cnt       = (int*)   (ws + (1u << 18));              // 200 KB
  int*    indptr    = (int*)   (ws + (2u << 18));              // 200 KB + 4
  int*    cursor    = (int*)   (ws + (3u << 18));              // 200 KB
  int*    chunkSums = (int*)   (ws + (1u << 20));              // tiny
  int2*   srcW      = (int2*)  (ws + 2u * (1u << 20));         // 6.4 MB
  ushort* W1T       = (ushort*)(ws + 9u * (1u << 20));         // 256 KB [512][256]
  ushort* W2T       = (ushort*)(ws + 9u * (1u << 20) + (1u << 19)); // 256 KB
  unsigned char* mask2 = (unsigned char*)(ws + 10u * (1u << 20)); // 1.6 MB
  ushort* x16       = (ushort*)(ws + 14u * (1u << 20));        // 25.6 MB [50000][256]
  ushort* aggB      = (ushort*)(ws + 40u * (1u << 20));        // 25.6 MB [M_PAD][256]
  ushort* h         = (ushort*)(ws + 66u * (1u << 20));        // 51.2 MB [M_PAD][512]
  ushort* hw2       = (ushort*)(ws + 118u* (1u << 20));        // 25.6 MB [M_PAD][256]

  constexpr U2 K1 = threefry2x32(0u, 42u, 0u, 0u);
  constexpr U2 K2 = threefry2x32(0u, 42u, 0u, 1u);

  // ---- CSR build ----
  (void)hipMemsetAsync(cnt, 0, N_NODES * sizeof(int), stream);
  (void)hipMemsetAsync(cursor, 0, N_NODES * sizeof(int), stream);
  deg_kernel<<<(N_EDGES + 255) / 256, 256, 0, stream>>>(col, cnt, N_EDGES);
  dinv_kernel<<<(N_NODES + 255) / 256, 256, 0, stream>>>(cnt, dinv, N_NODES);
  const int nChunks = (N_NODES + 1023) / 1024;
  scan_local<<<nChunks, 1024, 0, stream>>>(cnt, indptr, chunkSums, N_NODES);
  scan_chunks<<<1, 64, 0, stream>>>(chunkSums, nChunks);
  add_offsets<<<(N_NODES + 255) / 256, 256, 0, stream>>>(indptr, chunkSums, N_NODES, N_EDGES);
  build_csr<<<(N_EDGES + 255) / 256, 256, 0, stream>>>(row, col, indptr, cursor, dinv, srcW, N_EDGES);

  // ---- converts ----
  cvt_f32_bf16<<<(N_NODES * IN_C / 4 + 255) / 256, 256, 0, stream>>>(x, x16, N_NODES * IN_C / 4);
  wT_kernel<8><<<(IN_C * HID_C + 255) / 256, 256, 0, stream>>>(W1, W1T, HID_C, IN_C * HID_C);
  wT_kernel<9><<<(HID_C * OUT_C + 255) / 256, 256, 0, stream>>>(W2, W2T, OUT_C, HID_C * OUT_C);
  (void)hipMemsetAsync(aggB + (size_t)N_NODES * IN_C, 0, (size_t)(M_PAD - N_NODES) * IN_C * 2, stream);

  // ---- layer 1 ----
  gather16<false><<<(N_NODES + 3) / 4, 256, 0, stream>>>(
      x16, indptr, srcW, dinv, nullptr, aggB, nullptr, N_NODES);
  gemm_bf16<1><<<dim3(M_PAD / 128, HID_C / 128), 256, 0, stream>>>(
      aggB, W1T, h, M_PAD, IN_C, HID_C, b1, nullptr, K1.a, K1.b);

  // ---- layer 2 ----
  gemm_bf16<2><<<dim3(M_PAD / 128, OUT_C / 128), 256, 0, stream>>>(
      h, W2T, hw2, M_PAD, HID_C, OUT_C, nullptr, mask2, K2.a, K2.b);
  gather16<true><<<(N_NODES + 3) / 4, 256, 0, stream>>>(
      hw2, indptr, srcW, dinv, b2, out, mask2, N_NODES);
}

// Round 10
// 350.031 us; speedup vs baseline: 1.0716x; 1.0574x over previous
//
#include <hip/hip_runtime.h>
#include <stdint.h>

// ---------------------------------------------------------------------------
// GCN: agg1 = A_hat x (8-deep gather + layer1 mask gen)      [round-6 form]
//      h    = relu+drop(agg1 W1 + b1)   (MFMA GEMM, mask1 bit-test)
//      hw2  = h W2                      (MFMA GEMM + layer-2 mask gen)
//      out  = relu+drop(A_hat hw2 + b2) (8-deep gather + mask2 bit-test)
// GEMM uses swapped-operand MFMA: lane holds 4 contiguous cols -> direct 8B
// C stores, no LDS transpose. Staging single-buffer 32KB -> 5 blocks/CU.
// ---------------------------------------------------------------------------

#define N_NODES 50000
#define N_EDGES 800000
#define M_PAD   50048   // 391 * 128
#define IN_C 256
#define HID_C 512
#define OUT_C 256

typedef __attribute__((ext_vector_type(8))) short bf16x8;
typedef __attribute__((ext_vector_type(4))) float f32x4;

struct U2 { unsigned a, b; };

__host__ __device__ constexpr unsigned rotl32(unsigned x, int d) {
  return (x << d) | (x >> (32 - d));
}

#define TF_ROUND(r) { x0 += x1; x1 = rotl32(x1, (r)); x1 ^= x0; }

__host__ __device__ constexpr U2 threefry2x32(unsigned k0, unsigned k1,
                                              unsigned x0, unsigned x1) {
  unsigned ks2 = k0 ^ k1 ^ 0x1BD11BDAu;
  x0 += k0; x1 += k1;
  TF_ROUND(13) TF_ROUND(15) TF_ROUND(26) TF_ROUND(6)  x0 += k1;  x1 += ks2 + 1u;
  TF_ROUND(17) TF_ROUND(29) TF_ROUND(16) TF_ROUND(24) x0 += ks2; x1 += k0 + 2u;
  TF_ROUND(13) TF_ROUND(15) TF_ROUND(26) TF_ROUND(6)  x0 += k0;  x1 += k1 + 3u;
  TF_ROUND(17) TF_ROUND(29) TF_ROUND(16) TF_ROUND(24) x0 += k1;  x1 += ks2 + 4u;
  TF_ROUND(13) TF_ROUND(15) TF_ROUND(26) TF_ROUND(6)  x0 += ks2; x1 += k0 + 5u;
  return U2{x0, x1};
}

__device__ __forceinline__ ushort f2b(float f) {  // RTNE
  unsigned u = __builtin_bit_cast(unsigned, f);
  unsigned r = (u + 0x7fffu + ((u >> 16) & 1u)) >> 16;
  return (ushort)r;
}
__device__ __forceinline__ float b2f(ushort h) {
  unsigned u = (unsigned)h << 16;
  return __builtin_bit_cast(float, u);
}

__device__ __forceinline__ void gload16(const void* g, void* l) {
  __builtin_amdgcn_global_load_lds(
      (const __attribute__((address_space(1))) void*)g,
      (__attribute__((address_space(3))) void*)l, 16, 0, 0);
}

// ---------------------------------------------------------------------------
// degree / dinv / scan / CSR build (CSR entry = {src, dinv[src]})
// ---------------------------------------------------------------------------
__global__ void deg_kernel(const int* __restrict__ col, int* __restrict__ cnt, int E) {
  int e = blockIdx.x * 256 + threadIdx.x;
  if (e < E) atomicAdd(&cnt[col[e]], 1);
}

__global__ void dinv_kernel(const int* __restrict__ cnt, float* __restrict__ dinv, int N) {
  int n = blockIdx.x * 256 + threadIdx.x;
  if (n < N) dinv[n] = rsqrtf((float)cnt[n] + 1.0f);
}

__global__ __launch_bounds__(1024) void scan_local(const int* __restrict__ cnt,
                                                   int* __restrict__ indptr,
                                                   int* __restrict__ chunkSums, int n) {
  __shared__ int s[1024];
  int gid = blockIdx.x * 1024 + threadIdx.x;
  int v = (gid < n) ? cnt[gid] : 0;
  s[threadIdx.x] = v;
  __syncthreads();
#pragma unroll
  for (int off = 1; off < 1024; off <<= 1) {
    int t = (threadIdx.x >= off) ? s[threadIdx.x - off] : 0;
    __syncthreads();
    s[threadIdx.x] += t;
    __syncthreads();
  }
  if (gid < n) indptr[gid] = s[threadIdx.x] - v;
  if (threadIdx.x == 1023) chunkSums[blockIdx.x] = s[1023];
}

__global__ void scan_chunks(int* __restrict__ chunkSums, int nChunks) {
  if (threadIdx.x == 0 && blockIdx.x == 0) {
    int acc = 0;
    for (int i = 0; i < nChunks; ++i) { int t = chunkSums[i]; chunkSums[i] = acc; acc += t; }
  }
}

__global__ void add_offsets(int* __restrict__ indptr, const int* __restrict__ chunkSums,
                            int n, int total) {
  int gid = blockIdx.x * 256 + threadIdx.x;
  if (gid < n) indptr[gid] += chunkSums[gid >> 10];
  if (gid == 0) indptr[n] = total;
}

__global__ void build_csr(const int* __restrict__ row, const int* __restrict__ col,
                          const int* __restrict__ indptr, int* __restrict__ cursor,
                          const float* __restrict__ dinv,
                          int2* __restrict__ srcW, int E) {
  int e = blockIdx.x * 256 + threadIdx.x;
  if (e < E) {
    int r = row[e];
    int c = col[e];
    int p = indptr[c] + atomicAdd(&cursor[c], 1);
    srcW[p] = make_int2(r, __builtin_bit_cast(int, dinv[r]));
  }
}

// ---------------------------------------------------------------------------
// converts
// ---------------------------------------------------------------------------
__global__ void cvt_f32_bf16(const float* __restrict__ in, ushort* __restrict__ out, int n4) {
  int i = blockIdx.x * 256 + threadIdx.x;
  if (i < n4) {
    float4 v = *(const float4*)(in + (size_t)i * 4);
    ushort4 o = make_ushort4(f2b(v.x), f2b(v.y), f2b(v.z), f2b(v.w));
    *(ushort4*)(out + (size_t)i * 4) = o;
  }
}

template <int LOGK>
__global__ void wT_kernel(const float* __restrict__ W, ushort* __restrict__ WT, int N, int total) {
  int i = blockIdx.x * 256 + threadIdx.x;
  if (i < total) {
    int k = i & ((1 << LOGK) - 1);
    int n = i >> LOGK;
    WT[i] = f2b(W[(size_t)k * N + n]);
  }
}

// ---------------------------------------------------------------------------
// gather over CSR pairs (round-6 form): one wave per node, 64 lanes x 8B,
// 8-deep unrolled. EPI=false: bf16 out + layer-1 mask bitmap (8 threefry/lane).
// EPI=true: bias+relu+mask2-bit dropout, fp32 out.
// ---------------------------------------------------------------------------
#define ROW_ACC(vv, ww)                                                        \
  { a0 += b2f((vv).x) * (ww); a1 += b2f((vv).y) * (ww);                        \
    a2 += b2f((vv).z) * (ww); a3 += b2f((vv).w) * (ww); }

template <bool EPI>
__global__ __launch_bounds__(256) void gather8(const ushort* __restrict__ X,
                                               const int* __restrict__ indptr,
                                               const int2* __restrict__ srcW,
                                               const float* __restrict__ dinv,
                                               const float* __restrict__ bias,
                                               void* __restrict__ outp,
                                               unsigned char* __restrict__ maskGen,
                                               const unsigned char* __restrict__ maskUse,
                                               unsigned kk0, unsigned kk1, int N) {
  int wid = (blockIdx.x * 256 + threadIdx.x) >> 6;
  int lane = threadIdx.x & 63;
  if (wid >= N) return;
  int beg = __builtin_amdgcn_readfirstlane(indptr[wid]);
  int end = __builtin_amdgcn_readfirstlane(indptr[wid + 1]);
  float dc = dinv[wid];
  const int f0 = lane * 4;
  ushort4 sv = *(const ushort4*)(X + (size_t)wid * 256 + f0);
  float a0 = b2f(sv.x) * dc, a1 = b2f(sv.y) * dc,
        a2 = b2f(sv.z) * dc, a3 = b2f(sv.w) * dc;

  int e = beg;
  for (; e + 8 <= end; e += 8) {
    int2 p0 = srcW[e + 0], p1 = srcW[e + 1], p2 = srcW[e + 2], p3 = srcW[e + 3];
    int2 p4 = srcW[e + 4], p5 = srcW[e + 5], p6 = srcW[e + 6], p7 = srcW[e + 7];
    ushort4 v0 = *(const ushort4*)(X + (size_t)p0.x * 256 + f0);
    ushort4 v1 = *(const ushort4*)(X + (size_t)p1.x * 256 + f0);
    ushort4 v2 = *(const ushort4*)(X + (size_t)p2.x * 256 + f0);
    ushort4 v3 = *(const ushort4*)(X + (size_t)p3.x * 256 + f0);
    ushort4 v4 = *(const ushort4*)(X + (size_t)p4.x * 256 + f0);
    ushort4 v5 = *(const ushort4*)(X + (size_t)p5.x * 256 + f0);
    ushort4 v6 = *(const ushort4*)(X + (size_t)p6.x * 256 + f0);
    ushort4 v7 = *(const ushort4*)(X + (size_t)p7.x * 256 + f0);
    ROW_ACC(v0, __builtin_bit_cast(float, p0.y));
    ROW_ACC(v1, __builtin_bit_cast(float, p1.y));
    ROW_ACC(v2, __builtin_bit_cast(float, p2.y));
    ROW_ACC(v3, __builtin_bit_cast(float, p3.y));
    ROW_ACC(v4, __builtin_bit_cast(float, p4.y));
    ROW_ACC(v5, __builtin_bit_cast(float, p5.y));
    ROW_ACC(v6, __builtin_bit_cast(float, p6.y));
    ROW_ACC(v7, __builtin_bit_cast(float, p7.y));
  }
  for (; e + 2 <= end; e += 2) {
    int2 p0 = srcW[e + 0], p1 = srcW[e + 1];
    ushort4 v0 = *(const ushort4*)(X + (size_t)p0.x * 256 + f0);
    ushort4 v1 = *(const ushort4*)(X + (size_t)p1.x * 256 + f0);
    ROW_ACC(v0, __builtin_bit_cast(float, p0.y));
    ROW_ACC(v1, __builtin_bit_cast(float, p1.y));
  }
  if (e < end) {
    int2 p0 = srcW[e];
    ushort4 v0 = *(const ushort4*)(X + (size_t)p0.x * 256 + f0);
    ROW_ACC(v0, __builtin_bit_cast(float, p0.y));
  }
  a0 *= dc; a1 *= dc; a2 *= dc; a3 *= dc;

  if (EPI) {
    float4 bv = *(const float4*)(bias + f0);
    unsigned mk = maskUse[(size_t)wid * 32 + (lane >> 1)];
    int sh = (lane & 1) * 4;
    float v0 = fmaxf(a0 + bv.x, 0.f);
    float v1 = fmaxf(a1 + bv.y, 0.f);
    float v2 = fmaxf(a2 + bv.z, 0.f);
    float v3 = fmaxf(a3 + bv.w, 0.f);
    v0 = ((mk >> (sh + 0)) & 1u) ? 0.f : v0 * 2.0f;
    v1 = ((mk >> (sh + 1)) & 1u) ? 0.f : v1 * 2.0f;
    v2 = ((mk >> (sh + 2)) & 1u) ? 0.f : v2 * 2.0f;
    v3 = ((mk >> (sh + 3)) & 1u) ? 0.f : v3 * 2.0f;
    *(float4*)((float*)outp + (size_t)wid * 256 + f0) = make_float4(v0, v1, v2, v3);
  } else {
    uint2 o;
    o.x = (unsigned)f2b(a0) | ((unsigned)f2b(a1) << 16);
    o.y = (unsigned)f2b(a2) | ((unsigned)f2b(a3) << 16);
    *(uint2*)((ushort*)outp + (size_t)wid * 256 + f0) = o;
    // layer-1 dropout mask: this lane packs bits for h elements [gl*8, gl*8+8)
    unsigned gl = (unsigned)wid * 64u + (unsigned)lane;
    unsigned eb = gl * 8u;
    unsigned byte = 0;
#pragma unroll
    for (int j = 0; j < 8; ++j) {
      U2 r = threefry2x32(kk0, kk1, 0u, eb + (unsigned)j);
      byte |= (((r.a ^ r.b) >> 31) & 1u) << j;
    }
    maskGen[gl] = (unsigned char)byte;
  }
}

// ---------------------------------------------------------------------------
// bf16 MFMA GEMM: C[M,N] = A[M,K] @ BT[N,K]^T.  128x128 tile, BK=64, 4 waves,
// single-buffer 32KB staging, XOR-swizzled. SWAPPED-operand mfma: lane holds
// 4 contiguous cols -> direct 8B C stores (no LDS transpose).
// MODE 1: bias+relu+mask1-bit dropout, bf16 out.
// MODE 2: plain bf16 out + layer-2 dropout bitmask generation.
// ---------------------------------------------------------------------------
template <int MODE>
__global__ __launch_bounds__(256) void gemm_bf16(const ushort* __restrict__ A,
                                                 const ushort* __restrict__ BT,
                                                 ushort* __restrict__ C,
                                                 int M, int K, int N,
                                                 const float* __restrict__ bias,
                                                 const unsigned char* __restrict__ mask1,
                                                 unsigned char* __restrict__ maskOut,
                                                 unsigned kk0, unsigned kk1) {
  __shared__ __align__(16) ushort lds[16384];  // A 16KB | B 16KB
  const int tid = threadIdx.x;
  const int lane = tid & 63;
  const int wv = tid >> 6;
  const int wr = wv >> 1, wc = wv & 1;
  const int bm = blockIdx.x * 128;
  const int bn = blockIdx.y * 128;

  f32x4 acc[4][4] = {};
  const int xorv = (lane & 7) << 4;

  const int nt = K >> 6;
  for (int t = 0; t < nt; ++t) {
    const int k0 = t << 6;
#pragma unroll
    for (int l = 0; l < 4; ++l) {
      int cid = l * 256 + tid;
      int row = cid >> 3;
      int kcol = ((cid & 7) ^ (row & 7)) * 8;
      gload16(A + (size_t)(bm + row) * K + k0 + kcol, (void*)(lds + cid * 8));
      gload16(BT + (size_t)(bn + row) * K + k0 + kcol, (void*)(lds + 8192 + cid * 8));
    }
    __syncthreads();
    const char* Ab = (const char*)lds;
    const char* Bb = (const char*)(lds + 8192);
#pragma unroll
    for (int ks = 0; ks < 2; ++ks) {
      bf16x8 af[4], bf[4];
      const int kb = (ks * 64 + (lane >> 4) * 16) ^ xorv;
#pragma unroll
      for (int i = 0; i < 4; ++i) {
        int arow = wr * 64 + i * 16 + (lane & 15);
        af[i] = *(const bf16x8*)(Ab + arow * 128 + kb);
        int brow = wc * 64 + i * 16 + (lane & 15);
        bf[i] = *(const bf16x8*)(Bb + brow * 128 + kb);
      }
      // SWAPPED operands: D row-dim <- bf (n), col-dim (lane&15) <- af (m)
#pragma unroll
      for (int m = 0; m < 4; ++m)
#pragma unroll
        for (int n = 0; n < 4; ++n)
          acc[m][n] = __builtin_amdgcn_mfma_f32_16x16x32_bf16(bf[n], af[m], acc[m][n], 0, 0, 0);
    }
    __syncthreads();
  }

  // ---- epilogue: lane owns C[grow][gcol..gcol+3] per (m,n) -> direct 8B store
  const int growb = bm + wr * 64 + (lane & 15);
  const int gcolb = bn + wc * 64 + ((lane >> 4) << 2);
  float4 bias_v[4];
  if (MODE == 1) {
#pragma unroll
    for (int n = 0; n < 4; ++n) bias_v[n] = *(const float4*)(bias + gcolb + n * 16);
  }
#pragma unroll
  for (int m = 0; m < 4; ++m) {
    int grow = growb + m * 16;
    unsigned long long mrow = 0;
    if (MODE == 1)
      mrow = *(const unsigned long long*)(mask1 + (((size_t)grow * N + bn + wc * 64) >> 3));
#pragma unroll
    for (int n = 0; n < 4; ++n) {
      int gcol = gcolb + n * 16;
      float v[4];
#pragma unroll
      for (int r = 0; r < 4; ++r) {
        float x = acc[m][n][r];
        if (MODE == 1) {
          x = fmaxf(x + ((const float*)&bias_v[n])[r], 0.f);
          int bit = (gcol - (bn + wc * 64)) + r;
          x = ((mrow >> bit) & 1ull) ? 0.f : x * 2.0f;
        }
        v[r] = x;
      }
      uint2 o;
      o.x = (unsigned)f2b(v[0]) | ((unsigned)f2b(v[1]) << 16);
      o.y = (unsigned)f2b(v[2]) | ((unsigned)f2b(v[3]) << 16);
      *(uint2*)(C + (size_t)grow * N + gcol) = o;
    }
  }

  if (MODE == 2) {
    // layer-2 dropout bitmask for out[grow][bn+ch .. +64)
    int row = tid >> 1, ch = (tid & 1) * 64;
    int grow = bm + row;
    unsigned base = (unsigned)grow * (unsigned)N + (unsigned)(bn + ch);
    unsigned long long mword = 0;
#pragma unroll
    for (int j = 0; j < 64; ++j) {
      U2 rr = threefry2x32(kk0, kk1, 0u, base + (unsigned)j);
      mword |= (unsigned long long)(((rr.a ^ rr.b) >> 31) & 1u) << j;
    }
    *(unsigned long long*)(maskOut + (size_t)(base >> 3)) = mword;
  }
}

// ---------------------------------------------------------------------------
extern "C" void kernel_launch(void* const* d_in, const int* in_sizes, int n_in,
                              void* d_out, int out_size, void* d_ws, size_t ws_size,
                              hipStream_t stream) {
  const float* x  = (const float*)d_in[0];
  const int*   ei = (const int*)d_in[1];
  const float* W1 = (const float*)d_in[2];
  const float* b1 = (const float*)d_in[3];
  const float* W2 = (const float*)d_in[4];
  const float* b2 = (const float*)d_in[5];
  float* out = (float*)d_out;
  (void)in_sizes; (void)n_in; (void)out_size; (void)ws_size;

  const int* row = ei;
  const int* col = ei + N_EDGES;

  // workspace layout (bytes)
  char* ws = (char*)d_ws;
  float*  dinv      = (float*) (ws);                           // 200 KB
  int*    cnt       = (int*)   (ws + (1u << 18));              // 200 KB
  int*    indptr    = (int*)   (ws + (2u << 18));              // 200 KB + 4
  int*    cursor    = (int*)   (ws + (3u << 18));              // 200 KB
  int*    chunkSums = (int*)   (ws + (1u << 20));              // tiny
  int2*   srcW      = (int2*)  (ws + 2u * (1u << 20));         // 6.4 MB
  ushort* W1T       = (ushort*)(ws + 9u * (1u << 20));         // 256 KB [512][256]
  ushort* W2T       = (ushort*)(ws + 9u * (1u << 20) + (1u << 19)); // 256 KB
  unsigned char* mask1 = (unsigned char*)(ws + 10u * (1u << 20)); // 3.21 MB
  unsigned char* mask2 = (unsigned char*)(ws + 14u * (1u << 20)); // 1.61 MB
  ushort* x16       = (ushort*)(ws + 18u * (1u << 20));        // 25.6 MB [50000][256]
  ushort* aggB      = (ushort*)(ws + 44u * (1u << 20));        // 25.6 MB [M_PAD][256]
  ushort* h         = (ushort*)(ws + 70u * (1u << 20));        // 51.2 MB [M_PAD][512]
  ushort* hw2       = (ushort*)(ws + 122u* (1u << 20));        // 25.6 MB [M_PAD][256]

  constexpr U2 K1 = threefry2x32(0u, 42u, 0u, 0u);
  constexpr U2 K2 = threefry2x32(0u, 42u, 0u, 1u);

  // ---- CSR build ----
  (void)hipMemsetAsync(cnt, 0, N_NODES * sizeof(int), stream);
  (void)hipMemsetAsync(cursor, 0, N_NODES * sizeof(int), stream);
  deg_kernel<<<(N_EDGES + 255) / 256, 256, 0, stream>>>(col, cnt, N_EDGES);
  dinv_kernel<<<(N_NODES + 255) / 256, 256, 0, stream>>>(cnt, dinv, N_NODES);
  const int nChunks = (N_NODES + 1023) / 1024;
  scan_local<<<nChunks, 1024, 0, stream>>>(cnt, indptr, chunkSums, N_NODES);
  scan_chunks<<<1, 64, 0, stream>>>(chunkSums, nChunks);
  add_offsets<<<(N_NODES + 255) / 256, 256, 0, stream>>>(indptr, chunkSums, N_NODES, N_EDGES);
  build_csr<<<(N_EDGES + 255) / 256, 256, 0, stream>>>(row, col, indptr, cursor, dinv, srcW, N_EDGES);

  // ---- converts ----
  cvt_f32_bf16<<<(N_NODES * IN_C / 4 + 255) / 256, 256, 0, stream>>>(x, x16, N_NODES * IN_C / 4);
  wT_kernel<8><<<(IN_C * HID_C + 255) / 256, 256, 0, stream>>>(W1, W1T, HID_C, IN_C * HID_C);
  wT_kernel<9><<<(HID_C * OUT_C + 255) / 256, 256, 0, stream>>>(W2, W2T, OUT_C, HID_C * OUT_C);
  (void)hipMemsetAsync(aggB + (size_t)N_NODES * IN_C, 0, (size_t)(M_PAD - N_NODES) * IN_C * 2, stream);

  // ---- layer 1 ----
  gather8<false><<<(N_NODES + 3) / 4, 256, 0, stream>>>(
      x16, indptr, srcW, dinv, nullptr, aggB, mask1, nullptr, K1.a, K1.b, N_NODES);
  gemm_bf16<1><<<dim3(M_PAD / 128, HID_C / 128), 256, 0, stream>>>(
      aggB, W1T, h, M_PAD, IN_C, HID_C, b1, mask1, nullptr, 0u, 0u);

  // ---- layer 2 ----
  gemm_bf16<2><<<dim3(M_PAD / 128, OUT_C / 128), 256, 0, stream>>>(
      h, W2T, hw2, M_PAD, HID_C, OUT_C, nullptr, nullptr, mask2, K2.a, K2.b);
  gather8<true><<<(N_NODES + 3) / 4, 256, 0, stream>>>(
      hw2, indptr, srcW, dinv, b2, out, nullptr, mask2, 0u, 0u, N_NODES);
}